// Round 1
// 93.800 us; speedup vs baseline: 1.0675x; 1.0675x over previous
//
#include <hip/hip_runtime.h>
#include <math.h>

#define LOG2PI_F 1.8378770664093453f
#define LOG2E_F  1.4426950408889634f
#define LN2_F    0.6931471805599453f
#define EXP_NEG1 0.36787944117144233f

#define TI   32      // i-rows per block (2 per thread: il and il+16)
#define JSP  16      // j-splits (grid.y)
#define JCH  128     // j-rows per block = B/JSP (B=2048)
#define ROWF 52      // floats per AC row: a[16] b[16] c[16] prod [pad 3]

__device__ __forceinline__ float exp2_(float x) { return __builtin_amdgcn_exp2f(x); }
__device__ __forceinline__ float log2_(float x) { return __builtin_amdgcn_logf(x); }

// ws layout (floats), NOTHING pre-zeroed (all plain stores, no atomics):
//   AC  [B*52]          packed per-j coefficients
//   Rs  [JSP][17][B]    per-jsplit partial sums, [c][i] transposed for coalescing
//   PPa [prepBlks] PPb [prepBlks]   per-block lqzx / lprior partials
//   RP  [512]           per-block recon partials
//   LPa [logBlks] LPb [logBlks]     per-block lqz / lqzp partials

// ---------------------------------------------------------------- prep+recon
// blocks [0, prepBlks): one thread per (j,d) -> AC coefficients + lqzx/lprior
// blocks [prepBlks, prepBlks+512): grid-stride recon MAE
__global__ __launch_bounds__(256) void k_prep_recon(
        const float* __restrict__ mu, const float* __restrict__ lv,
        const float* __restrict__ z, const int* __restrict__ nds,
        const float4* __restrict__ x, const float4* __restrict__ r,
        float* __restrict__ AC, float* __restrict__ PPa, float* __restrict__ PPb,
        float* __restrict__ RP, int B, int n4, int prepBlks) {
    __shared__ float ra[4], rb[4];
    const int lane = threadIdx.x & 63, wv = threadIdx.x >> 6;

    if ((int)blockIdx.x < prepBlks) {
        int idx = blockIdx.x * 256 + threadIdx.x;
        int j = idx >> 4, d = idx & 15;
        float m = mu[idx], l = lv[idx], zz = z[idx];
        float is = __expf(-l);
        float a = -0.5f * LOG2E_F * is;                               // log2-domain
        float b = -2.0f * a * m;
        float ec = fmaf(-0.5f * LOG2E_F, l + LOG2PI_F, a * m * m);    // log2(C')

        float Nf = (float)(*nds);
        float Mf = (float)(B - 1);
        float strat = (Nf - Mf) / (Nf * Mf);
        float w = (j == 0) ? (1.0f / Nf) : ((j == 1) ? strat : (1.0f / Mf));

        float* row = AC + (size_t)j * ROWF;
        row[d] = a;
        row[16 + d] = b;
        row[32 + d] = w * exp2_(ec);
        float es = ec;
        es += __shfl_xor(es, 1); es += __shfl_xor(es, 2);
        es += __shfl_xor(es, 4); es += __shfl_xor(es, 8);
        if (d == 0) row[48] = w * exp2_(es);

        float t = zz - m;
        float ga = -0.5f * (fmaf(t * t, is, l) + LOG2PI_F);
        float gb = -0.5f * (fmaf(zz * zz, EXP_NEG1, 1.0f) + LOG2PI_F);
        #pragma unroll
        for (int off = 32; off > 0; off >>= 1) { ga += __shfl_down(ga, off); gb += __shfl_down(gb, off); }
        if (lane == 0) { ra[wv] = ga; rb[wv] = gb; }
        __syncthreads();
        if (threadIdx.x == 0) {
            PPa[blockIdx.x] = ra[0] + ra[1] + ra[2] + ra[3];
            PPb[blockIdx.x] = rb[0] + rb[1] + rb[2] + rb[3];
        }
    } else {
        int bid = blockIdx.x - prepBlks;
        float s = 0.0f;
        for (int idx = bid * 256 + threadIdx.x; idx < n4; idx += 512 * 256) {
            float4 a = x[idx], b = r[idx];
            s += fabsf(a.x - b.x) + fabsf(a.y - b.y) + fabsf(a.z - b.z) + fabsf(a.w - b.w);
        }
        #pragma unroll
        for (int off = 32; off > 0; off >>= 1) s += __shfl_down(s, off);
        if (lane == 0) ra[wv] = s;
        __syncthreads();
        if (threadIdx.x == 0) RP[bid] = ra[0] + ra[1] + ra[2] + ra[3];
    }
}

// ---------------------------------------------------------------- pairwise
// Two i-rows per thread: the same 13 LDS reads per j-row feed 128 pairs
// instead of 64 (LDS-issue pipe was the bottleneck: ~150 pipe-cyc / wave-k).
#define DIM2(AQ, BQ, CQ, comp, dd, SA, SB) \
    e = fmaf(AQ.comp, va2[dd], BQ.comp * va[dd]); SA += e; sda[dd] = fmaf(CQ.comp, exp2_(e), sda[dd]); \
    e = fmaf(AQ.comp, vb2[dd], BQ.comp * vb[dd]); SB += e; sdb[dd] = fmaf(CQ.comp, exp2_(e), sdb[dd]);

// grid (B/TI, JSP); block 256 = 16 il x 16 jg. Single-stage LDS (whole j-slice).
__global__ __launch_bounds__(256) void k_pair(const float* __restrict__ AC,
                                              const float* __restrict__ z,
                                              float* __restrict__ Rs,
                                              int B, int jch) {
    __shared__ float sbuf[JCH * ROWF];      // 26.6 KB
    __shared__ float red[4][TI][17];        // 8.7 KB

    const int il = threadIdx.x & 15;
    const int jg = threadIdx.x >> 4;
    const int i0 = blockIdx.x * TI + il;    // second row: i0 + 16
    const int jbase = blockIdx.y * jch;

    // stage full j-slice: jch*ROWF/4 = 1664 float4
    {
        const float4* g = (const float4*)(AC + (size_t)jbase * ROWF);
        float4* dst = (float4*)sbuf;
        #pragma unroll
        for (int k = 0; k < 7; ++k) {
            int idx = threadIdx.x + k * 256;
            if (idx < (JCH * ROWF) / 4) dst[idx] = g[idx];
        }
    }

    float va[16], va2[16], vb[16], vb2[16];
    {
        const float4* zp = (const float4*)(z + (size_t)i0 * 16);
        float4 z0 = zp[0], z1 = zp[1], z2 = zp[2], z3 = zp[3];
        va[0]=z0.x; va[1]=z0.y; va[2]=z0.z; va[3]=z0.w;
        va[4]=z1.x; va[5]=z1.y; va[6]=z1.z; va[7]=z1.w;
        va[8]=z2.x; va[9]=z2.y; va[10]=z2.z; va[11]=z2.w;
        va[12]=z3.x; va[13]=z3.y; va[14]=z3.z; va[15]=z3.w;
        const float4* zq = (const float4*)(z + (size_t)(i0 + 16) * 16);
        float4 y0 = zq[0], y1 = zq[1], y2 = zq[2], y3 = zq[3];
        vb[0]=y0.x; vb[1]=y0.y; vb[2]=y0.z; vb[3]=y0.w;
        vb[4]=y1.x; vb[5]=y1.y; vb[6]=y1.z; vb[7]=y1.w;
        vb[8]=y2.x; vb[9]=y2.y; vb[10]=y2.z; vb[11]=y2.w;
        vb[12]=y3.x; vb[13]=y3.y; vb[14]=y3.z; vb[15]=y3.w;
        #pragma unroll
        for (int d = 0; d < 16; d++) { va2[d] = va[d] * va[d]; vb2[d] = vb[d] * vb[d]; }
    }

    float sda[16], sdb[16];
    #pragma unroll
    for (int d = 0; d < 16; d++) { sda[d] = 0.0f; sdb[d] = 0.0f; }
    float stA = 0.0f, stB = 0.0f;

    __syncthreads();

    const int nk = jch >> 4;                // 8
    for (int k = 0; k < nk; ++k) {
        const float* rp = sbuf + (jg + 16 * k) * ROWF;
        const float4* r4 = (const float4*)rp;
        float sa0 = 0.0f, sa1 = 0.0f, sb0 = 0.0f, sb1 = 0.0f, e;
        {   // dims 0-7 (split loads in halves to cap staging VGPRs)
            float4 A0 = r4[0], A1 = r4[1], Bq0 = r4[4], Bq1 = r4[5], C0 = r4[8], C1 = r4[9];
            DIM2(A0, Bq0, C0, x, 0, sa0, sb0)  DIM2(A0, Bq0, C0, y, 1, sa1, sb1)
            DIM2(A0, Bq0, C0, z, 2, sa0, sb0)  DIM2(A0, Bq0, C0, w, 3, sa1, sb1)
            DIM2(A1, Bq1, C1, x, 4, sa0, sb0)  DIM2(A1, Bq1, C1, y, 5, sa1, sb1)
            DIM2(A1, Bq1, C1, z, 6, sa0, sb0)  DIM2(A1, Bq1, C1, w, 7, sa1, sb1)
        }
        {   // dims 8-15
            float4 A2 = r4[2], A3 = r4[3], Bq2 = r4[6], Bq3 = r4[7], C2 = r4[10], C3 = r4[11];
            DIM2(A2, Bq2, C2, x, 8, sa0, sb0)  DIM2(A2, Bq2, C2, y, 9, sa1, sb1)
            DIM2(A2, Bq2, C2, z, 10, sa0, sb0) DIM2(A2, Bq2, C2, w, 11, sa1, sb1)
            DIM2(A3, Bq3, C3, x, 12, sa0, sb0) DIM2(A3, Bq3, C3, y, 13, sa1, sb1)
            DIM2(A3, Bq3, C3, z, 14, sa0, sb0) DIM2(A3, Bq3, C3, w, 15, sa1, sb1)
        }
        float P = rp[48];
        stA = fmaf(P, exp2_(sa0 + sa1), stA);
        stB = fmaf(P, exp2_(sb0 + sb1), stB);
    }

    // reduce over jg within wave (jg bits 0-1 = lane bits 4-5)
    #pragma unroll
    for (int msk = 16; msk <= 32; msk <<= 1) {
        stA += __shfl_xor(stA, msk);
        stB += __shfl_xor(stB, msk);
        #pragma unroll
        for (int d = 0; d < 16; d++) {
            sda[d] += __shfl_xor(sda[d], msk);
            sdb[d] += __shfl_xor(sdb[d], msk);
        }
    }
    const int lane = threadIdx.x & 63, wv = threadIdx.x >> 6;
    if (lane < 16) {
        red[wv][lane][0] = stA;
        red[wv][lane + 16][0] = stB;
        #pragma unroll
        for (int d = 0; d < 16; d++) {
            red[wv][lane][1 + d] = sda[d];
            red[wv][lane + 16][1 + d] = sdb[d];
        }
    }
    __syncthreads();
    // plain stores to this j-split's slice (no atomics, transposed [c][i] layout)
    for (int t = threadIdx.x; t < TI * 17; t += 256) {
        int il2 = t & 31, c = t >> 5;
        float s = red[0][il2][c] + red[1][il2][c] + red[2][il2][c] + red[3][il2][c];
        Rs[((size_t)blockIdx.y * 17 + c) * B + blockIdx.x * TI + il2] = s;
    }
}

// ---------------------------------------------------------------- logs
// One thread per i: sum JSP slices (coalesced), logs + W[B-2,0] patch.
__global__ __launch_bounds__(256) void k_logs(const float* __restrict__ Rs,
                                              const float* __restrict__ AC,
                                              const float* __restrict__ z,
                                              const int* __restrict__ nds,
                                              float* __restrict__ LPa,
                                              float* __restrict__ LPb, int B) {
    int i = blockIdx.x * 256 + threadIdx.x;
    float S = 0.0f, Sd[16];
    #pragma unroll
    for (int d = 0; d < 16; d++) Sd[d] = 0.0f;
    for (int sp = 0; sp < JSP; ++sp) {
        const float* base = Rs + (size_t)sp * 17 * B + i;
        S += base[0];
        #pragma unroll
        for (int d = 0; d < 16; d++) Sd[d] += base[(size_t)(1 + d) * B];
    }

    if (i == B - 2) {
        // prep folded w0 = 1/N into row 0, but W[B-2,0] = strat: add delta.
        const float* row0 = AC;
        const float* vv = z + (size_t)i * 16;
        float Nf = (float)(*nds);
        float Mf = (float)(B - 1);
        float strat = (Nf - Mf) / (Nf * Mf);
        float dwN = (strat - 1.0f / Nf) * Nf;
        float s2 = 0.0f;
        #pragma unroll
        for (int d = 0; d < 16; d++) {
            float vd = vv[d];
            float e = fmaf(row0[d], vd * vd, row0[16 + d] * vd);
            s2 += e;
            Sd[d] += dwN * row0[32 + d] * exp2_(e);
        }
        S += dwN * row0[48] * exp2_(s2);
    }

    float lqz = log2_(S) * LN2_F;
    float lqzp = 0.0f;
    #pragma unroll
    for (int d = 0; d < 16; d++) lqzp += log2_(Sd[d]);
    lqzp *= LN2_F;

    #pragma unroll
    for (int off = 32; off > 0; off >>= 1) {
        lqz += __shfl_down(lqz, off);
        lqzp += __shfl_down(lqzp, off);
    }
    __shared__ float ra[4], rb[4];
    int lane = threadIdx.x & 63, wv = threadIdx.x >> 6;
    if (lane == 0) { ra[wv] = lqz; rb[wv] = lqzp; }
    __syncthreads();
    if (threadIdx.x == 0) {
        LPa[blockIdx.x] = ra[0] + ra[1] + ra[2] + ra[3];
        LPb[blockIdx.x] = rb[0] + rb[1] + rb[2] + rb[3];
    }
}

// ---------------------------------------------------------------- final
__global__ void k_final(const float* __restrict__ RP, const float* __restrict__ PPa,
                        const float* __restrict__ PPb, const float* __restrict__ LPa,
                        const float* __restrict__ LPb, float* __restrict__ out,
                        float invBF, float invB, int prepBlks, int logBlks) {
    int tid = threadIdx.x;
    float sr = 0.0f, sga = 0.0f, sgb = 0.0f, slz = 0.0f, slp = 0.0f;
    for (int t = tid; t < 512; t += 256) sr += RP[t];
    for (int t = tid; t < prepBlks; t += 256) { sga += PPa[t]; sgb += PPb[t]; }
    for (int t = tid; t < logBlks; t += 256) { slz += LPa[t]; slp += LPb[t]; }
    #pragma unroll
    for (int off = 32; off > 0; off >>= 1) {
        sr += __shfl_down(sr, off);   sga += __shfl_down(sga, off);
        sgb += __shfl_down(sgb, off); slz += __shfl_down(slz, off);
        slp += __shfl_down(slp, off);
    }
    __shared__ float red[4][5];
    int lane = tid & 63, wv = tid >> 6;
    if (lane == 0) {
        red[wv][0] = sr; red[wv][1] = sga; red[wv][2] = sgb;
        red[wv][3] = slz; red[wv][4] = slp;
    }
    __syncthreads();
    if (tid == 0) {
        float R  = red[0][0] + red[1][0] + red[2][0] + red[3][0];
        float GA = red[0][1] + red[1][1] + red[2][1] + red[3][1];
        float GB = red[0][2] + red[1][2] + red[2][2] + red[3][2];
        float LZ = red[0][3] + red[1][3] + red[2][3] + red[3][3];
        float LQ = red[0][4] + red[1][4] + red[2][4] + red[3][4];
        out[0] = R * invBF + (GA + 3.0f * LZ - 3.0f * LQ - GB) * invB;
    }
}

extern "C" void kernel_launch(void* const* d_in, const int* in_sizes, int n_in,
                              void* d_out, int out_size, void* d_ws, size_t ws_size,
                              hipStream_t stream) {
    const float* x   = (const float*)d_in[0];
    const float* rec = (const float*)d_in[1];
    const float* mu  = (const float*)d_in[2];
    const float* lv  = (const float*)d_in[3];
    const float* z   = (const float*)d_in[4];
    const int*   nds = (const int*)d_in[5];

    const int BD = in_sizes[2];        // B * 16
    const int B  = BD / 16;
    const int BF = in_sizes[0];        // B * F
    const int n4 = BF / 4;
    const int prepBlks = BD / 256;     // 128 at B=2048
    const int logBlks  = B / 256;      // 8

    float* AC  = (float*)d_ws;                         // B*52
    float* Rs  = AC + (size_t)B * 52;                  // JSP*17*B
    float* PPa = Rs + (size_t)JSP * 17 * B;
    float* PPb = PPa + prepBlks;
    float* RP  = PPb + prepBlks;                       // 512
    float* LPa = RP + 512;
    float* LPb = LPa + logBlks;

    // no memset: every ws word consumed is plainly written first (no atomics)
    k_prep_recon<<<prepBlks + 512, 256, 0, stream>>>(mu, lv, z, nds,
        (const float4*)x, (const float4*)rec, AC, PPa, PPb, RP, B, n4, prepBlks);
    dim3 gp(B / TI, JSP);
    k_pair <<<gp, 256, 0, stream>>>(AC, z, Rs, B, B / JSP);
    k_logs <<<logBlks, 256, 0, stream>>>(Rs, AC, z, nds, LPa, LPb, B);
    k_final<<<1, 256, 0, stream>>>(RP, PPa, PPb, LPa, LPb, (float*)d_out,
                                   1.0f / (float)BF, 1.0f / (float)B, prepBlks, logBlks);
}